// Round 18
// baseline (280.553 us; speedup 1.0000x reference)
//
#include <hip/hip_runtime.h>
#include <hip/hip_fp16.h>

#define HID 128

typedef _Float16 h2_t __attribute__((ext_vector_type(2)));
typedef _Float16 half8 __attribute__((ext_vector_type(8)));
typedef float f32x4 __attribute__((ext_vector_type(4)));

static __device__ __forceinline__ float fdot2(__half2 a, __half2 b, float c) {
    return __builtin_amdgcn_fdot2(__builtin_bit_cast(h2_t, a), __builtin_bit_cast(h2_t, b), c, false);
}

// ---------------- fast zero ----------------
__global__ __launch_bounds__(256) void zero_kernel(int4* __restrict__ p, int n4) {
    int i = blockIdx.x * 256 + threadIdx.x;
    if (i < n4) p[i] = make_int4(0, 0, 0, 0);
}

// ---------------- degree histogram, XCD/dst-range partitioned ----------------
__global__ __launch_bounds__(256) void deg_kernel(const int* __restrict__ ei,
                                                  int* __restrict__ deg, int E, int n) {
    int grp  = blockIdx.x & 7;
    int blk  = blockIdx.x >> 3;
    int nblk = gridDim.x >> 3;
    int lo = (int)(((long long)n * grp) >> 3);
    int hi = (int)(((long long)n * (grp + 1)) >> 3);
    for (int e = blk * 256 + threadIdx.x; e < E; e += nblk * 256) {
        int dst = ei[E + e];
        if (dst >= lo && dst < hi) atomicAdd(&deg[dst], 1);
    }
}

// ---------------- scan stage 1 ----------------
__global__ __launch_bounds__(256) void part_kernel(const int* __restrict__ deg,
                                                   int* __restrict__ part, int n) {
    int i = blockIdx.x * 256 + threadIdx.x;
    int v = (i < n) ? deg[i] : 0;
    #pragma unroll
    for (int m = 1; m < 64; m <<= 1) v += __shfl_xor(v, m);
    __shared__ int w[4];
    int lane = threadIdx.x & 63, wv = threadIdx.x >> 6;
    if (lane == 0) w[wv] = v;
    __syncthreads();
    if (threadIdx.x == 0) part[blockIdx.x] = w[0] + w[1] + w[2] + w[3];
}

// ---------------- scan stage 2 ----------------
__global__ __launch_bounds__(1024) void scanpart_kernel(int* __restrict__ part, int nb) {
    __shared__ int s[1024];
    int t = threadIdx.x;
    int v = (t < nb) ? part[t] : 0;
    int orig = v;
    s[t] = v;
    __syncthreads();
    for (int off = 1; off < 1024; off <<= 1) {
        int u = (t >= off) ? s[t - off] : 0;
        __syncthreads();
        s[t] += u;
        __syncthreads();
    }
    if (t < nb) part[t] = s[t] - orig;   // exclusive
}

// ---------------- scan stage 3 ----------------
__global__ __launch_bounds__(256) void rp_kernel(const int* __restrict__ deg,
                                                 const int* __restrict__ part,
                                                 int* __restrict__ rp,
                                                 int* __restrict__ cursor, int n) {
    int tid = threadIdx.x, lane = tid & 63, wv = tid >> 6;
    int i = blockIdx.x * 256 + tid;
    int v = (i < n) ? deg[i] : 0;
    int orig = v;
    #pragma unroll
    for (int off = 1; off < 64; off <<= 1) {
        int t = __shfl_up(v, off);
        if (lane >= off) v += t;
    }
    __shared__ int wsum[4];
    if (lane == 63) wsum[wv] = v;
    __syncthreads();
    int wbase = 0;
    #pragma unroll
    for (int w = 0; w < 4; ++w) if (w < wv) wbase += wsum[w];
    int excl = part[blockIdx.x] + wbase + v - orig;
    if (i < n) { rp[i] = excl; cursor[i] = excl; }
    if (i == n - 1) rp[n] = excl + orig;
}

// ---------------- CSR fill, XCD/dst-range partitioned ----------------
__global__ __launch_bounds__(256) void fill_kernel(const int* __restrict__ ei,
                                                   int* __restrict__ cursor,
                                                   int* __restrict__ csr_src, int E, int n) {
    int grp  = blockIdx.x & 7;
    int blk  = blockIdx.x >> 3;
    int nblk = gridDim.x >> 3;
    int lo = (int)(((long long)n * grp) >> 3);
    int hi = (int)(((long long)n * (grp + 1)) >> 3);
    for (int e = blk * 256 + threadIdx.x; e < E; e += nblk * 256) {
        int dst = ei[E + e];
        if (dst >= lo && dst < hi) {
            int pos = atomicAdd(&cursor[dst], 1);
            csr_src[pos] = ei[e];
        }
    }
}

// ---------------- 128-dim pull aggregation v2 ----------------
// 8 B/lane loads: 32 lanes cover a 256 B row; wave halves take even/odd neighbors
// (8 rows in flight via 4 accumulators per half); shfl_xor(32) merges halves.
__global__ __launch_bounds__(256) void aggp_kernel(const int* __restrict__ rp,
                                                   const int* __restrict__ ci,
                                                   const __half* __restrict__ h16,
                                                   __half* __restrict__ agg16, int n) {
    int node = (blockIdx.x * 256 + threadIdx.x) >> 6;
    if (node >= n) return;
    int lane = threadIdx.x & 63;
    int half = lane >> 5;
    int c4 = (lane & 31) * 4;          // 4 halves per lane
    int beg = rp[node], end = rp[node + 1];
    float4 A0 = make_float4(0.f, 0.f, 0.f, 0.f);
    float4 A1 = make_float4(0.f, 0.f, 0.f, 0.f);
    float4 A2 = make_float4(0.f, 0.f, 0.f, 0.f);
    float4 A3 = make_float4(0.f, 0.f, 0.f, 0.f);
    int j = beg + half;
    for (; j + 6 < end; j += 8) {      // this half handles j, j+2, j+4, j+6
        int s0 = ci[j], s1 = ci[j + 2], s2 = ci[j + 4], s3 = ci[j + 6];
        float2 r0 = *(const float2*)(h16 + (size_t)s0 * HID + c4);
        float2 r1 = *(const float2*)(h16 + (size_t)s1 * HID + c4);
        float2 r2 = *(const float2*)(h16 + (size_t)s2 * HID + c4);
        float2 r3 = *(const float2*)(h16 + (size_t)s3 * HID + c4);
        const __half2* p0 = (const __half2*)&r0;
        const __half2* p1 = (const __half2*)&r1;
        const __half2* p2 = (const __half2*)&r2;
        const __half2* p3 = (const __half2*)&r3;
        float2 l0 = __half22float2(p0[0]), h0 = __half22float2(p0[1]);
        float2 l1 = __half22float2(p1[0]), h1 = __half22float2(p1[1]);
        float2 l2 = __half22float2(p2[0]), h2 = __half22float2(p2[1]);
        float2 l3 = __half22float2(p3[0]), h3 = __half22float2(p3[1]);
        A0.x += l0.x; A0.y += l0.y; A0.z += h0.x; A0.w += h0.y;
        A1.x += l1.x; A1.y += l1.y; A1.z += h1.x; A1.w += h1.y;
        A2.x += l2.x; A2.y += l2.y; A2.z += h2.x; A2.w += h2.y;
        A3.x += l3.x; A3.y += l3.y; A3.z += h3.x; A3.w += h3.y;
    }
    for (; j < end; j += 2) {
        int s0 = ci[j];
        float2 r0 = *(const float2*)(h16 + (size_t)s0 * HID + c4);
        const __half2* p0 = (const __half2*)&r0;
        float2 l0 = __half22float2(p0[0]), h0 = __half22float2(p0[1]);
        A0.x += l0.x; A0.y += l0.y; A0.z += h0.x; A0.w += h0.y;
    }
    float ax = A0.x + A1.x + A2.x + A3.x;
    float ay = A0.y + A1.y + A2.y + A3.y;
    float az = A0.z + A1.z + A2.z + A3.z;
    float aw = A0.w + A1.w + A2.w + A3.w;
    ax += __shfl_xor(ax, 32);
    ay += __shfl_xor(ay, 32);
    az += __shfl_xor(az, 32);
    aw += __shfl_xor(aw, 32);
    if (lane < 32) {
        float inv = 1.0f / fmaxf((float)(end - beg), 1.0f);
        __half2 o01 = __floats2half2_rn(ax * inv, ay * inv);
        __half2 o23 = __floats2half2_rn(az * inv, aw * inv);
        float2 pack;
        ((__half2*)&pack)[0] = o01;
        ((__half2*)&pack)[1] = o23;
        *(float2*)(agg16 + (size_t)node * HID + c4) = pack;
    }
}

// ---------------- layer 0 v2: lane-per-neighbor gather (all neighbors in flight) ----------------
__global__ __launch_bounds__(256) void layer0_kernel(
    const float* __restrict__ x, const int* __restrict__ rp, const int* __restrict__ ci,
    const float* __restrict__ w_l, const float* __restrict__ b_l, const float* __restrict__ w_r,
    const float* __restrict__ ln_w, const float* __restrict__ ln_b,
    __half* __restrict__ h16, int n)
{
    int node = (blockIdx.x * 256 + threadIdx.x) >> 6;
    int lane = threadIdx.x & 63;
    if (node >= n) return;
    int beg = rp[node], end = rp[node + 1];
    float a[11];
    #pragma unroll
    for (int k = 0; k < 11; ++k) a[k] = 0.f;
    for (int j = beg + lane; j < end; j += 64) {
        int src = ci[j];
        const float* xr = x + (size_t)src * 11;
        #pragma unroll
        for (int k = 0; k < 11; ++k) a[k] += xr[k];
    }
    // fold 64 lanes per component; result broadcast to all lanes
    #pragma unroll
    for (int k = 0; k < 11; ++k) {
        float v = a[k];
        #pragma unroll
        for (int m = 1; m < 64; m <<= 1) v += __shfl_xor(v, m);
        a[k] = v;
    }
    float inv = 1.0f / fmaxf((float)(end - beg), 1.0f);
    float v0 = b_l[lane], v1 = b_l[lane + 64];
    #pragma unroll
    for (int k = 0; k < 11; ++k) {
        float ak = a[k] * inv;
        float xi = x[(size_t)node * 11 + k];
        v0 += ak * w_l[k * HID + lane]      + xi * w_r[k * HID + lane];
        v1 += ak * w_l[k * HID + lane + 64] + xi * w_r[k * HID + lane + 64];
    }
    float s = v0 + v1, s2 = v0 * v0 + v1 * v1;
    #pragma unroll
    for (int m = 1; m < 64; m <<= 1) { s += __shfl_xor(s, m); s2 += __shfl_xor(s2, m); }
    float mu  = s * (1.0f / HID);
    float var = s2 * (1.0f / HID) - mu * mu;
    float rstd = rsqrtf(var + 1e-5f);
    float o0 = fmaxf((v0 - mu) * rstd * ln_w[lane]      + ln_b[lane],      0.0f);
    float o1 = fmaxf((v1 - mu) * rstd * ln_w[lane + 64] + ln_b[lane + 64], 0.0f);
    h16[(size_t)node * HID + lane]      = __float2half_rn(o0);
    h16[(size_t)node * HID + lane + 64] = __float2half_rn(o1);
}

// ---------------- MFMA B-fragment weight pack ----------------
__global__ __launch_bounds__(256) void wfrag_kernel(const float* __restrict__ wl,
                                                    const float* __restrict__ wr,
                                                    __half* __restrict__ wf) {
    int idx = blockIdx.x * 256 + threadIdx.x;   // over 8*8*64 = 4096
    if (idx >= 4096) return;
    int kt = idx >> 9;
    int ct = (idx >> 6) & 7;
    int l  = idx & 63;
    int col = ct * 16 + (l & 15);
    int kbase = kt * 32 + (l >> 4) * 8;
    #pragma unroll
    for (int j = 0; j < 8; ++j) {
        int k = kbase + j;
        const float* W = (k < HID) ? wl : wr;
        int kk = k & (HID - 1);
        wf[(size_t)idx * 8 + j] = __float2half_rn(W[kk * HID + col]);
    }
}

// ---------------- cls weight pack ----------------
__global__ __launch_bounds__(256) void wpack_cls_kernel(const float* __restrict__ w0,
                                                        __half2* __restrict__ w0p) {
    int idx = blockIdx.x * 256 + threadIdx.x;   // over 64*64
    if (idx >= 64 * 64) return;
    int p = idx >> 6, c = idx & 63;
    w0p[idx] = __floats2half2_rn(w0[(2 * p) * 64 + c], w0[(2 * p + 1) * 64 + c]);
}

// ---------------- layers 1/2: MFMA GEMM (64 nodes/block, 4 waves x 16-row tiles) ----------------
__global__ __launch_bounds__(256) void layer_kernel(
    const __half* __restrict__ agg16, const __half* __restrict__ h16in,
    const __half* __restrict__ wf, const float* __restrict__ b_l,
    const float* __restrict__ ln_w, const float* __restrict__ ln_b,
    __half* __restrict__ h16out, int n)
{
    __shared__ __half lds[64][264];   // [node][agg(0..127) | h_in(128..255)]
    int base = blockIdx.x * 64;
    int tid = threadIdx.x;
    #pragma unroll
    for (int i = 0; i < 8; ++i) {
        int idx = tid + i * 256;
        int row = idx >> 5;
        int c4  = (idx & 31) * 4;
        int node = base + row;
        float2 a = make_float2(0.f, 0.f);
        float2 h = make_float2(0.f, 0.f);
        if (node < n) {
            a = *(const float2*)(agg16 + (size_t)node * HID + c4);
            h = *(const float2*)(h16in + (size_t)node * HID + c4);
        }
        *(float2*)&lds[row][c4]       = a;
        *(float2*)&lds[row][HID + c4] = h;
    }
    __syncthreads();

    int w = tid >> 6;
    int l = tid & 63;
    int g = l >> 4, cl = l & 15;

    f32x4 acc[8];
    #pragma unroll
    for (int ct = 0; ct < 8; ++ct) acc[ct] = (f32x4){0.f, 0.f, 0.f, 0.f};

    #pragma unroll
    for (int kt = 0; kt < 8; ++kt) {
        half8 a = *(const half8*)&lds[w * 16 + cl][kt * 32 + g * 8];
        #pragma unroll
        for (int ct = 0; ct < 8; ++ct) {
            half8 b = *(const half8*)(wf + ((size_t)(kt * 8 + ct) * 64 + l) * 8);
            acc[ct] = __builtin_amdgcn_mfma_f32_16x16x32_f16(a, b, acc[ct], 0, 0, 0);
        }
    }

    float bl8[8], gw8[8], gb8[8];
    #pragma unroll
    for (int ct = 0; ct < 8; ++ct) {
        bl8[ct] = b_l[ct * 16 + cl];
        gw8[ct] = ln_w[ct * 16 + cl];
        gb8[ct] = ln_b[ct * 16 + cl];
    }

    #pragma unroll
    for (int r = 0; r < 4; ++r) {
        int row = w * 16 + g * 4 + r;
        float v[8];
        float s = 0.f, s2 = 0.f;
        #pragma unroll
        for (int ct = 0; ct < 8; ++ct) {
            v[ct] = acc[ct][r] + bl8[ct];
            s += v[ct]; s2 += v[ct] * v[ct];
        }
        #pragma unroll
        for (int m = 1; m < 16; m <<= 1) { s += __shfl_xor(s, m); s2 += __shfl_xor(s2, m); }
        float mu  = s * (1.0f / HID);
        float var = s2 * (1.0f / HID) - mu * mu;
        float rstd = rsqrtf(var + 1e-5f);
        int node = base + row;
        if (node < n) {
            #pragma unroll
            for (int ct = 0; ct < 8; ++ct) {
                float o = fmaxf((v[ct] - mu) * rstd * gw8[ct] + gb8[ct], 0.f)
                          + __half2float(lds[row][HID + ct * 16 + cl]);
                h16out[(size_t)node * HID + ct * 16 + cl] = __float2half_rn(o);
            }
        }
    }
}

// ---------------- classifier: dot2, 32 nodes/block (8/wave), 2 accumulators ----------------
__global__ __launch_bounds__(256) void cls_kernel(
    const __half* __restrict__ h, const __half2* __restrict__ w0p, const float* __restrict__ b0,
    const float* __restrict__ w1, const float* __restrict__ b1, float* __restrict__ out, int n)
{
    __shared__ __half2 w0s[64 * 64];   // 16 KB, k-pair-packed
    int tid = threadIdx.x;
    #pragma unroll
    for (int i = 0; i < 16; ++i) w0s[tid + i * 256] = w0p[tid + i * 256];
    __syncthreads();
    int lane = tid & 63, wv = tid >> 6;
    float bb0 = b0[lane], ww1 = w1[lane], bb1 = b1[0];
    #pragma unroll 1
    for (int q = 0; q < 8; ++q) {
        int node = blockIdx.x * 32 + wv * 8 + q;
        if (node >= n) break;
        const __half2* hr = (const __half2*)(h + (size_t)node * HID);
        float s0 = 0.f, s1 = 0.f;
        #pragma unroll
        for (int p = 0; p < 64; p += 2) {
            s0 = fdot2(hr[p],     w0s[(p + 0) * 64 + lane], s0);
            s1 = fdot2(hr[p + 1], w0s[(p + 1) * 64 + lane], s1);
        }
        float s = fmaxf(s0 + s1 + bb0, 0.f);
        float t = s * ww1;
        #pragma unroll
        for (int m = 1; m < 64; m <<= 1) t += __shfl_xor(t, m);
        if (lane == 0) out[node] = t + bb1;
    }
}

extern "C" void kernel_launch(void* const* d_in, const int* in_sizes, int n_in,
                              void* d_out, int out_size, void* d_ws, size_t ws_size,
                              hipStream_t stream) {
    const float* x  = (const float*)d_in[0];
    const int*   ei = (const int*)d_in[1];     // integer inputs arrive as int32
    const float* w_l0 = (const float*)d_in[2];
    const float* b_l0 = (const float*)d_in[3];
    const float* w_r0 = (const float*)d_in[4];
    const float* lnw0 = (const float*)d_in[5];
    const float* lnb0 = (const float*)d_in[6];
    const float* w_l1 = (const float*)d_in[7];
    const float* b_l1 = (const float*)d_in[8];
    const float* w_r1 = (const float*)d_in[9];
    const float* lnw1 = (const float*)d_in[10];
    const float* lnb1 = (const float*)d_in[11];
    const float* w_l2 = (const float*)d_in[12];
    const float* b_l2 = (const float*)d_in[13];
    const float* w_r2 = (const float*)d_in[14];
    const float* lnw2 = (const float*)d_in[15];
    const float* lnb2 = (const float*)d_in[16];
    const float* c_w0 = (const float*)d_in[17];
    const float* c_b0 = (const float*)d_in[18];
    const float* c_w1 = (const float*)d_in[19];
    const float* c_b1 = (const float*)d_in[20];
    float* out = (float*)d_out;

    int N = in_sizes[0] / 11;
    int E = in_sizes[1] / 2;
    int nb = (N + 255) / 256;

    // workspace: [deg: N][rp: N+1][cursor: N][csr: E][part: nb]
    //            [h16][agg16][wf1][wf2][w0p]
    int*     deg    = (int*)d_ws;
    int*     rp     = deg + N;
    int*     cursor = rp + (N + 1);
    int*     csr    = cursor + N;
    int*     part   = csr + E;
    __half*  h16    = (__half*)(part + ((nb + 63) & ~63));
    __half*  agg16  = h16 + (size_t)N * HID;
    __half*  wf1    = agg16 + (size_t)N * HID;
    __half*  wf2    = wf1 + 4096 * 8;
    __half2* w0p    = (__half2*)(wf2 + 4096 * 8);

    // ---- CSR build (dst-range partitioned across XCDs) + weight packs ----
    int n4 = (N + 3) / 4;   // over-zeroing <=3 ints into rp is harmless (rp rewritten)
    zero_kernel<<<(n4 + 255) / 256, 256, 0, stream>>>((int4*)deg, n4);
    deg_kernel<<<8 * 512, 256, 0, stream>>>(ei, deg, E, N);
    part_kernel<<<nb, 256, 0, stream>>>(deg, part, N);
    scanpart_kernel<<<1, 1024, 0, stream>>>(part, nb);
    rp_kernel<<<nb, 256, 0, stream>>>(deg, part, rp, cursor, N);
    fill_kernel<<<8 * 512, 256, 0, stream>>>(ei, cursor, csr, E, N);
    wfrag_kernel<<<16, 256, 0, stream>>>(w_l1, w_r1, wf1);
    wfrag_kernel<<<16, 256, 0, stream>>>(w_l2, w_r2, wf2);
    wpack_cls_kernel<<<16, 256, 0, stream>>>(c_w0, w0p);

    int nodeBlocks = (N + 3) / 4;

    // ---- layer 0 ----  h0 -> h16
    layer0_kernel<<<nodeBlocks, 256, 0, stream>>>(x, rp, csr, w_l0, b_l0, w_r0, lnw0, lnb0, h16, N);

    // ---- layer 1 ----  gather(h16)->agg16 ; layer(agg16, h16) -> h16
    aggp_kernel<<<nodeBlocks, 256, 0, stream>>>(rp, csr, h16, agg16, N);
    layer_kernel<<<(N + 63) / 64, 256, 0, stream>>>(agg16, h16, wf1, b_l1, lnw1, lnb1, h16, N);

    // ---- layer 2 ----
    aggp_kernel<<<nodeBlocks, 256, 0, stream>>>(rp, csr, h16, agg16, N);
    layer_kernel<<<(N + 63) / 64, 256, 0, stream>>>(agg16, h16, wf2, b_l2, lnw2, lnb2, h16, N);

    // ---- classifier ----
    cls_kernel<<<(N + 31) / 32, 256, 0, stream>>>(h16, w0p, c_b0, c_w1, c_b1, out, N);
}

// Round 19
// 279.000 us; speedup vs baseline: 1.0056x; 1.0056x over previous
//
#include <hip/hip_runtime.h>
#include <hip/hip_fp16.h>

#define HID 128

typedef _Float16 h2_t __attribute__((ext_vector_type(2)));
typedef _Float16 half8 __attribute__((ext_vector_type(8)));
typedef float f32x4 __attribute__((ext_vector_type(4)));

static __device__ __forceinline__ float fdot2(__half2 a, __half2 b, float c) {
    return __builtin_amdgcn_fdot2(__builtin_bit_cast(h2_t, a), __builtin_bit_cast(h2_t, b), c, false);
}

// ---------------- fast zero ----------------
__global__ __launch_bounds__(256) void zero_kernel(int4* __restrict__ p, int n4) {
    int i = blockIdx.x * 256 + threadIdx.x;
    if (i < n4) p[i] = make_int4(0, 0, 0, 0);
}

// ---------------- degree histogram, XCD/dst-range partitioned ----------------
__global__ __launch_bounds__(256) void deg_kernel(const int* __restrict__ ei,
                                                  int* __restrict__ deg, int E, int n) {
    int grp  = blockIdx.x & 7;
    int blk  = blockIdx.x >> 3;
    int nblk = gridDim.x >> 3;
    int lo = (int)(((long long)n * grp) >> 3);
    int hi = (int)(((long long)n * (grp + 1)) >> 3);
    for (int e = blk * 256 + threadIdx.x; e < E; e += nblk * 256) {
        int dst = ei[E + e];
        if (dst >= lo && dst < hi) atomicAdd(&deg[dst], 1);
    }
}

// ---------------- scan stage 1 ----------------
__global__ __launch_bounds__(256) void part_kernel(const int* __restrict__ deg,
                                                   int* __restrict__ part, int n) {
    int i = blockIdx.x * 256 + threadIdx.x;
    int v = (i < n) ? deg[i] : 0;
    #pragma unroll
    for (int m = 1; m < 64; m <<= 1) v += __shfl_xor(v, m);
    __shared__ int w[4];
    int lane = threadIdx.x & 63, wv = threadIdx.x >> 6;
    if (lane == 0) w[wv] = v;
    __syncthreads();
    if (threadIdx.x == 0) part[blockIdx.x] = w[0] + w[1] + w[2] + w[3];
}

// ---------------- scan stage 2 ----------------
__global__ __launch_bounds__(1024) void scanpart_kernel(int* __restrict__ part, int nb) {
    __shared__ int s[1024];
    int t = threadIdx.x;
    int v = (t < nb) ? part[t] : 0;
    int orig = v;
    s[t] = v;
    __syncthreads();
    for (int off = 1; off < 1024; off <<= 1) {
        int u = (t >= off) ? s[t - off] : 0;
        __syncthreads();
        s[t] += u;
        __syncthreads();
    }
    if (t < nb) part[t] = s[t] - orig;   // exclusive
}

// ---------------- scan stage 3 ----------------
__global__ __launch_bounds__(256) void rp_kernel(const int* __restrict__ deg,
                                                 const int* __restrict__ part,
                                                 int* __restrict__ rp,
                                                 int* __restrict__ cursor, int n) {
    int tid = threadIdx.x, lane = tid & 63, wv = tid >> 6;
    int i = blockIdx.x * 256 + tid;
    int v = (i < n) ? deg[i] : 0;
    int orig = v;
    #pragma unroll
    for (int off = 1; off < 64; off <<= 1) {
        int t = __shfl_up(v, off);
        if (lane >= off) v += t;
    }
    __shared__ int wsum[4];
    if (lane == 63) wsum[wv] = v;
    __syncthreads();
    int wbase = 0;
    #pragma unroll
    for (int w = 0; w < 4; ++w) if (w < wv) wbase += wsum[w];
    int excl = part[blockIdx.x] + wbase + v - orig;
    if (i < n) { rp[i] = excl; cursor[i] = excl; }
    if (i == n - 1) rp[n] = excl + orig;
}

// ---------------- CSR fill, XCD/dst-range partitioned ----------------
__global__ __launch_bounds__(256) void fill_kernel(const int* __restrict__ ei,
                                                   int* __restrict__ cursor,
                                                   int* __restrict__ csr_src, int E, int n) {
    int grp  = blockIdx.x & 7;
    int blk  = blockIdx.x >> 3;
    int nblk = gridDim.x >> 3;
    int lo = (int)(((long long)n * grp) >> 3);
    int hi = (int)(((long long)n * (grp + 1)) >> 3);
    for (int e = blk * 256 + threadIdx.x; e < E; e += nblk * 256) {
        int dst = ei[E + e];
        if (dst >= lo && dst < hi) {
            int pos = atomicAdd(&cursor[dst], 1);
            csr_src[pos] = ei[e];
        }
    }
}

// ---------------- 128-dim pull aggregation v2 (kept from R18; ~neutral) ----------------
__global__ __launch_bounds__(256) void aggp_kernel(const int* __restrict__ rp,
                                                   const int* __restrict__ ci,
                                                   const __half* __restrict__ h16,
                                                   __half* __restrict__ agg16, int n) {
    int node = (blockIdx.x * 256 + threadIdx.x) >> 6;
    if (node >= n) return;
    int lane = threadIdx.x & 63;
    int half = lane >> 5;
    int c4 = (lane & 31) * 4;
    int beg = rp[node], end = rp[node + 1];
    float4 A0 = make_float4(0.f, 0.f, 0.f, 0.f);
    float4 A1 = make_float4(0.f, 0.f, 0.f, 0.f);
    float4 A2 = make_float4(0.f, 0.f, 0.f, 0.f);
    float4 A3 = make_float4(0.f, 0.f, 0.f, 0.f);
    int j = beg + half;
    for (; j + 6 < end; j += 8) {
        int s0 = ci[j], s1 = ci[j + 2], s2 = ci[j + 4], s3 = ci[j + 6];
        float2 r0 = *(const float2*)(h16 + (size_t)s0 * HID + c4);
        float2 r1 = *(const float2*)(h16 + (size_t)s1 * HID + c4);
        float2 r2 = *(const float2*)(h16 + (size_t)s2 * HID + c4);
        float2 r3 = *(const float2*)(h16 + (size_t)s3 * HID + c4);
        const __half2* p0 = (const __half2*)&r0;
        const __half2* p1 = (const __half2*)&r1;
        const __half2* p2 = (const __half2*)&r2;
        const __half2* p3 = (const __half2*)&r3;
        float2 l0 = __half22float2(p0[0]), h0 = __half22float2(p0[1]);
        float2 l1 = __half22float2(p1[0]), h1 = __half22float2(p1[1]);
        float2 l2 = __half22float2(p2[0]), h2 = __half22float2(p2[1]);
        float2 l3 = __half22float2(p3[0]), h3 = __half22float2(p3[1]);
        A0.x += l0.x; A0.y += l0.y; A0.z += h0.x; A0.w += h0.y;
        A1.x += l1.x; A1.y += l1.y; A1.z += h1.x; A1.w += h1.y;
        A2.x += l2.x; A2.y += l2.y; A2.z += h2.x; A2.w += h2.y;
        A3.x += l3.x; A3.y += l3.y; A3.z += h3.x; A3.w += h3.y;
    }
    for (; j < end; j += 2) {
        int s0 = ci[j];
        float2 r0 = *(const float2*)(h16 + (size_t)s0 * HID + c4);
        const __half2* p0 = (const __half2*)&r0;
        float2 l0 = __half22float2(p0[0]), h0 = __half22float2(p0[1]);
        A0.x += l0.x; A0.y += l0.y; A0.z += h0.x; A0.w += h0.y;
    }
    float ax = A0.x + A1.x + A2.x + A3.x;
    float ay = A0.y + A1.y + A2.y + A3.y;
    float az = A0.z + A1.z + A2.z + A3.z;
    float aw = A0.w + A1.w + A2.w + A3.w;
    ax += __shfl_xor(ax, 32);
    ay += __shfl_xor(ay, 32);
    az += __shfl_xor(az, 32);
    aw += __shfl_xor(aw, 32);
    if (lane < 32) {
        float inv = 1.0f / fmaxf((float)(end - beg), 1.0f);
        __half2 o01 = __floats2half2_rn(ax * inv, ay * inv);
        __half2 o23 = __floats2half2_rn(az * inv, aw * inv);
        float2 pack;
        ((__half2*)&pack)[0] = o01;
        ((__half2*)&pack)[1] = o23;
        *(float2*)(agg16 + (size_t)node * HID + c4) = pack;
    }
}

// ---------------- layer-0 aggregation: one THREAD per (node, k) — 550k threads ----------------
// 11 consecutive threads share ci[] reads (same line) and read 44 contiguous bytes of x.
// Serial deg-deep chain per thread is hidden by full-machine TLP.
__global__ __launch_bounds__(256) void agg0_kernel(const float* __restrict__ x,
                                                   const int* __restrict__ rp,
                                                   const int* __restrict__ ci,
                                                   float* __restrict__ agg0, int n) {
    int idx = blockIdx.x * 256 + threadIdx.x;
    if (idx >= n * 11) return;
    int node = idx / 11;
    int k = idx - node * 11;
    int beg = rp[node], end = rp[node + 1];
    float a = 0.f, b = 0.f;
    int j = beg;
    for (; j + 1 < end; j += 2) {
        a += x[(size_t)ci[j] * 11 + k];
        b += x[(size_t)ci[j + 1] * 11 + k];
    }
    if (j < end) a += x[(size_t)ci[j] * 11 + k];
    agg0[idx] = (a + b) / fmaxf((float)(end - beg), 1.0f);
}

// ---------------- layer 0 v3: matmul-only (reads precomputed agg0) ----------------
__global__ __launch_bounds__(256) void layer0_kernel(
    const float* __restrict__ x, const float* __restrict__ agg0,
    const float* __restrict__ w_l, const float* __restrict__ b_l, const float* __restrict__ w_r,
    const float* __restrict__ ln_w, const float* __restrict__ ln_b,
    __half* __restrict__ h16, int n)
{
    int node = (blockIdx.x * 256 + threadIdx.x) >> 6;
    int lane = threadIdx.x & 63;
    if (node >= n) return;
    float aggk = (lane < 11) ? agg0[(size_t)node * 11 + lane] : 0.f;
    float v0 = b_l[lane], v1 = b_l[lane + 64];
    #pragma unroll
    for (int k = 0; k < 11; ++k) {
        float a  = __shfl(aggk, k);
        float xi = x[(size_t)node * 11 + k];
        v0 += a * w_l[k * HID + lane]      + xi * w_r[k * HID + lane];
        v1 += a * w_l[k * HID + lane + 64] + xi * w_r[k * HID + lane + 64];
    }
    float s = v0 + v1, s2 = v0 * v0 + v1 * v1;
    #pragma unroll
    for (int m = 1; m < 64; m <<= 1) { s += __shfl_xor(s, m); s2 += __shfl_xor(s2, m); }
    float mu  = s * (1.0f / HID);
    float var = s2 * (1.0f / HID) - mu * mu;
    float rstd = rsqrtf(var + 1e-5f);
    float o0 = fmaxf((v0 - mu) * rstd * ln_w[lane]      + ln_b[lane],      0.0f);
    float o1 = fmaxf((v1 - mu) * rstd * ln_w[lane + 64] + ln_b[lane + 64], 0.0f);
    h16[(size_t)node * HID + lane]      = __float2half_rn(o0);
    h16[(size_t)node * HID + lane + 64] = __float2half_rn(o1);
}

// ---------------- MFMA B-fragment weight pack ----------------
__global__ __launch_bounds__(256) void wfrag_kernel(const float* __restrict__ wl,
                                                    const float* __restrict__ wr,
                                                    __half* __restrict__ wf) {
    int idx = blockIdx.x * 256 + threadIdx.x;   // over 8*8*64 = 4096
    if (idx >= 4096) return;
    int kt = idx >> 9;
    int ct = (idx >> 6) & 7;
    int l  = idx & 63;
    int col = ct * 16 + (l & 15);
    int kbase = kt * 32 + (l >> 4) * 8;
    #pragma unroll
    for (int j = 0; j < 8; ++j) {
        int k = kbase + j;
        const float* W = (k < HID) ? wl : wr;
        int kk = k & (HID - 1);
        wf[(size_t)idx * 8 + j] = __float2half_rn(W[kk * HID + col]);
    }
}

// ---------------- cls weight pack ----------------
__global__ __launch_bounds__(256) void wpack_cls_kernel(const float* __restrict__ w0,
                                                        __half2* __restrict__ w0p) {
    int idx = blockIdx.x * 256 + threadIdx.x;   // over 64*64
    if (idx >= 64 * 64) return;
    int p = idx >> 6, c = idx & 63;
    w0p[idx] = __floats2half2_rn(w0[(2 * p) * 64 + c], w0[(2 * p + 1) * 64 + c]);
}

// ---------------- layers 1/2: MFMA GEMM (64 nodes/block, 4 waves x 16-row tiles) ----------------
__global__ __launch_bounds__(256) void layer_kernel(
    const __half* __restrict__ agg16, const __half* __restrict__ h16in,
    const __half* __restrict__ wf, const float* __restrict__ b_l,
    const float* __restrict__ ln_w, const float* __restrict__ ln_b,
    __half* __restrict__ h16out, int n)
{
    __shared__ __half lds[64][264];   // [node][agg(0..127) | h_in(128..255)]
    int base = blockIdx.x * 64;
    int tid = threadIdx.x;
    #pragma unroll
    for (int i = 0; i < 8; ++i) {
        int idx = tid + i * 256;
        int row = idx >> 5;
        int c4  = (idx & 31) * 4;
        int node = base + row;
        float2 a = make_float2(0.f, 0.f);
        float2 h = make_float2(0.f, 0.f);
        if (node < n) {
            a = *(const float2*)(agg16 + (size_t)node * HID + c4);
            h = *(const float2*)(h16in + (size_t)node * HID + c4);
        }
        *(float2*)&lds[row][c4]       = a;
        *(float2*)&lds[row][HID + c4] = h;
    }
    __syncthreads();

    int w = tid >> 6;
    int l = tid & 63;
    int g = l >> 4, cl = l & 15;

    f32x4 acc[8];
    #pragma unroll
    for (int ct = 0; ct < 8; ++ct) acc[ct] = (f32x4){0.f, 0.f, 0.f, 0.f};

    #pragma unroll
    for (int kt = 0; kt < 8; ++kt) {
        half8 a = *(const half8*)&lds[w * 16 + cl][kt * 32 + g * 8];
        #pragma unroll
        for (int ct = 0; ct < 8; ++ct) {
            half8 b = *(const half8*)(wf + ((size_t)(kt * 8 + ct) * 64 + l) * 8);
            acc[ct] = __builtin_amdgcn_mfma_f32_16x16x32_f16(a, b, acc[ct], 0, 0, 0);
        }
    }

    float bl8[8], gw8[8], gb8[8];
    #pragma unroll
    for (int ct = 0; ct < 8; ++ct) {
        bl8[ct] = b_l[ct * 16 + cl];
        gw8[ct] = ln_w[ct * 16 + cl];
        gb8[ct] = ln_b[ct * 16 + cl];
    }

    #pragma unroll
    for (int r = 0; r < 4; ++r) {
        int row = w * 16 + g * 4 + r;
        float v[8];
        float s = 0.f, s2 = 0.f;
        #pragma unroll
        for (int ct = 0; ct < 8; ++ct) {
            v[ct] = acc[ct][r] + bl8[ct];
            s += v[ct]; s2 += v[ct] * v[ct];
        }
        #pragma unroll
        for (int m = 1; m < 16; m <<= 1) { s += __shfl_xor(s, m); s2 += __shfl_xor(s2, m); }
        float mu  = s * (1.0f / HID);
        float var = s2 * (1.0f / HID) - mu * mu;
        float rstd = rsqrtf(var + 1e-5f);
        int node = base + row;
        if (node < n) {
            #pragma unroll
            for (int ct = 0; ct < 8; ++ct) {
                float o = fmaxf((v[ct] - mu) * rstd * gw8[ct] + gb8[ct], 0.f)
                          + __half2float(lds[row][HID + ct * 16 + cl]);
                h16out[(size_t)node * HID + ct * 16 + cl] = __float2half_rn(o);
            }
        }
    }
}

// ---------------- classifier: dot2, 32 nodes/block (8/wave), 2 accumulators ----------------
__global__ __launch_bounds__(256) void cls_kernel(
    const __half* __restrict__ h, const __half2* __restrict__ w0p, const float* __restrict__ b0,
    const float* __restrict__ w1, const float* __restrict__ b1, float* __restrict__ out, int n)
{
    __shared__ __half2 w0s[64 * 64];   // 16 KB, k-pair-packed
    int tid = threadIdx.x;
    #pragma unroll
    for (int i = 0; i < 16; ++i) w0s[tid + i * 256] = w0p[tid + i * 256];
    __syncthreads();
    int lane = tid & 63, wv = tid >> 6;
    float bb0 = b0[lane], ww1 = w1[lane], bb1 = b1[0];
    #pragma unroll 1
    for (int q = 0; q < 8; ++q) {
        int node = blockIdx.x * 32 + wv * 8 + q;
        if (node >= n) break;
        const __half2* hr = (const __half2*)(h + (size_t)node * HID);
        float s0 = 0.f, s1 = 0.f;
        #pragma unroll
        for (int p = 0; p < 64; p += 2) {
            s0 = fdot2(hr[p],     w0s[(p + 0) * 64 + lane], s0);
            s1 = fdot2(hr[p + 1], w0s[(p + 1) * 64 + lane], s1);
        }
        float s = fmaxf(s0 + s1 + bb0, 0.f);
        float t = s * ww1;
        #pragma unroll
        for (int m = 1; m < 64; m <<= 1) t += __shfl_xor(t, m);
        if (lane == 0) out[node] = t + bb1;
    }
}

extern "C" void kernel_launch(void* const* d_in, const int* in_sizes, int n_in,
                              void* d_out, int out_size, void* d_ws, size_t ws_size,
                              hipStream_t stream) {
    const float* x  = (const float*)d_in[0];
    const int*   ei = (const int*)d_in[1];     // integer inputs arrive as int32
    const float* w_l0 = (const float*)d_in[2];
    const float* b_l0 = (const float*)d_in[3];
    const float* w_r0 = (const float*)d_in[4];
    const float* lnw0 = (const float*)d_in[5];
    const float* lnb0 = (const float*)d_in[6];
    const float* w_l1 = (const float*)d_in[7];
    const float* b_l1 = (const float*)d_in[8];
    const float* w_r1 = (const float*)d_in[9];
    const float* lnw1 = (const float*)d_in[10];
    const float* lnb1 = (const float*)d_in[11];
    const float* w_l2 = (const float*)d_in[12];
    const float* b_l2 = (const float*)d_in[13];
    const float* w_r2 = (const float*)d_in[14];
    const float* lnw2 = (const float*)d_in[15];
    const float* lnb2 = (const float*)d_in[16];
    const float* c_w0 = (const float*)d_in[17];
    const float* c_b0 = (const float*)d_in[18];
    const float* c_w1 = (const float*)d_in[19];
    const float* c_b1 = (const float*)d_in[20];
    float* out = (float*)d_out;

    int N = in_sizes[0] / 11;
    int E = in_sizes[1] / 2;
    int nb = (N + 255) / 256;

    // workspace: [deg: N][rp: N+1][cursor: N][csr: E][part: nb]
    //            [agg0: N*11 floats][h16][agg16][wf1][wf2][w0p]
    int*     deg    = (int*)d_ws;
    int*     rp     = deg + N;
    int*     cursor = rp + (N + 1);
    int*     csr    = cursor + N;
    int*     part   = csr + E;
    float*   agg0   = (float*)(part + ((nb + 63) & ~63));
    __half*  h16    = (__half*)(agg0 + (size_t)N * 11);
    __half*  agg16  = h16 + (size_t)N * HID;
    __half*  wf1    = agg16 + (size_t)N * HID;
    __half*  wf2    = wf1 + 4096 * 8;
    __half2* w0p    = (__half2*)(wf2 + 4096 * 8);

    // ---- CSR build (dst-range partitioned across XCDs) + weight packs ----
    int n4 = (N + 3) / 4;   // over-zeroing <=3 ints into rp is harmless (rp rewritten)
    zero_kernel<<<(n4 + 255) / 256, 256, 0, stream>>>((int4*)deg, n4);
    deg_kernel<<<8 * 512, 256, 0, stream>>>(ei, deg, E, N);
    part_kernel<<<nb, 256, 0, stream>>>(deg, part, N);
    scanpart_kernel<<<1, 1024, 0, stream>>>(part, nb);
    rp_kernel<<<nb, 256, 0, stream>>>(deg, part, rp, cursor, N);
    fill_kernel<<<8 * 512, 256, 0, stream>>>(ei, cursor, csr, E, N);
    wfrag_kernel<<<16, 256, 0, stream>>>(w_l1, w_r1, wf1);
    wfrag_kernel<<<16, 256, 0, stream>>>(w_l2, w_r2, wf2);
    wpack_cls_kernel<<<16, 256, 0, stream>>>(c_w0, w0p);

    int nodeBlocks = (N + 3) / 4;

    // ---- layer 0 ----  agg0 (thread per node,k) ; mm -> h16
    agg0_kernel<<<((N * 11) + 255) / 256, 256, 0, stream>>>(x, rp, csr, agg0, N);
    layer0_kernel<<<nodeBlocks, 256, 0, stream>>>(x, agg0, w_l0, b_l0, w_r0, lnw0, lnb0, h16, N);

    // ---- layer 1 ----  gather(h16)->agg16 ; layer(agg16, h16) -> h16
    aggp_kernel<<<nodeBlocks, 256, 0, stream>>>(rp, csr, h16, agg16, N);
    layer_kernel<<<(N + 63) / 64, 256, 0, stream>>>(agg16, h16, wf1, b_l1, lnw1, lnb1, h16, N);

    // ---- layer 2 ----
    aggp_kernel<<<nodeBlocks, 256, 0, stream>>>(rp, csr, h16, agg16, N);
    layer_kernel<<<(N + 63) / 64, 256, 0, stream>>>(agg16, h16, wf2, b_l2, lnw2, lnb2, h16, N);

    // ---- classifier ----
    cls_kernel<<<(N + 31) / 32, 256, 0, stream>>>(h16, w0p, c_b0, c_w1, c_b1, out, N);
}

// Round 20
// 273.748 us; speedup vs baseline: 1.0249x; 1.0192x over previous
//
#include <hip/hip_runtime.h>
#include <hip/hip_fp16.h>

#define HID 128

typedef _Float16 h2_t __attribute__((ext_vector_type(2)));
typedef _Float16 half8 __attribute__((ext_vector_type(8)));
typedef float f32x4 __attribute__((ext_vector_type(4)));

static __device__ __forceinline__ float fdot2(__half2 a, __half2 b, float c) {
    return __builtin_amdgcn_fdot2(__builtin_bit_cast(h2_t, a), __builtin_bit_cast(h2_t, b), c, false);
}

// ---------------- fast zero ----------------
__global__ __launch_bounds__(256) void zero_kernel(int4* __restrict__ p, int n4) {
    int i = blockIdx.x * 256 + threadIdx.x;
    if (i < n4) p[i] = make_int4(0, 0, 0, 0);
}

// ---------------- degree histogram, XCD/dst-range partitioned ----------------
__global__ __launch_bounds__(256) void deg_kernel(const int* __restrict__ ei,
                                                  int* __restrict__ deg, int E, int n) {
    int grp  = blockIdx.x & 7;
    int blk  = blockIdx.x >> 3;
    int nblk = gridDim.x >> 3;
    int lo = (int)(((long long)n * grp) >> 3);
    int hi = (int)(((long long)n * (grp + 1)) >> 3);
    for (int e = blk * 256 + threadIdx.x; e < E; e += nblk * 256) {
        int dst = ei[E + e];
        if (dst >= lo && dst < hi) atomicAdd(&deg[dst], 1);
    }
}

// ---------------- scan stage 1 ----------------
__global__ __launch_bounds__(256) void part_kernel(const int* __restrict__ deg,
                                                   int* __restrict__ part, int n) {
    int i = blockIdx.x * 256 + threadIdx.x;
    int v = (i < n) ? deg[i] : 0;
    #pragma unroll
    for (int m = 1; m < 64; m <<= 1) v += __shfl_xor(v, m);
    __shared__ int w[4];
    int lane = threadIdx.x & 63, wv = threadIdx.x >> 6;
    if (lane == 0) w[wv] = v;
    __syncthreads();
    if (threadIdx.x == 0) part[blockIdx.x] = w[0] + w[1] + w[2] + w[3];
}

// ---------------- scan stage 2 ----------------
__global__ __launch_bounds__(1024) void scanpart_kernel(int* __restrict__ part, int nb) {
    __shared__ int s[1024];
    int t = threadIdx.x;
    int v = (t < nb) ? part[t] : 0;
    int orig = v;
    s[t] = v;
    __syncthreads();
    for (int off = 1; off < 1024; off <<= 1) {
        int u = (t >= off) ? s[t - off] : 0;
        __syncthreads();
        s[t] += u;
        __syncthreads();
    }
    if (t < nb) part[t] = s[t] - orig;   // exclusive
}

// ---------------- scan stage 3 ----------------
__global__ __launch_bounds__(256) void rp_kernel(const int* __restrict__ deg,
                                                 const int* __restrict__ part,
                                                 int* __restrict__ rp,
                                                 int* __restrict__ cursor, int n) {
    int tid = threadIdx.x, lane = tid & 63, wv = tid >> 6;
    int i = blockIdx.x * 256 + tid;
    int v = (i < n) ? deg[i] : 0;
    int orig = v;
    #pragma unroll
    for (int off = 1; off < 64; off <<= 1) {
        int t = __shfl_up(v, off);
        if (lane >= off) v += t;
    }
    __shared__ int wsum[4];
    if (lane == 63) wsum[wv] = v;
    __syncthreads();
    int wbase = 0;
    #pragma unroll
    for (int w = 0; w < 4; ++w) if (w < wv) wbase += wsum[w];
    int excl = part[blockIdx.x] + wbase + v - orig;
    if (i < n) { rp[i] = excl; cursor[i] = excl; }
    if (i == n - 1) rp[n] = excl + orig;
}

// ---------------- CSR fill, XCD/dst-range partitioned ----------------
__global__ __launch_bounds__(256) void fill_kernel(const int* __restrict__ ei,
                                                   int* __restrict__ cursor,
                                                   int* __restrict__ csr_src, int E, int n) {
    int grp  = blockIdx.x & 7;
    int blk  = blockIdx.x >> 3;
    int nblk = gridDim.x >> 3;
    int lo = (int)(((long long)n * grp) >> 3);
    int hi = (int)(((long long)n * (grp + 1)) >> 3);
    for (int e = blk * 256 + threadIdx.x; e < E; e += nblk * 256) {
        int dst = ei[E + e];
        if (dst >= lo && dst < hi) {
            int pos = atomicAdd(&cursor[dst], 1);
            csr_src[pos] = ei[e];
        }
    }
}

// ---------------- 128-dim pull aggregation v2 ----------------
__global__ __launch_bounds__(256) void aggp_kernel(const int* __restrict__ rp,
                                                   const int* __restrict__ ci,
                                                   const __half* __restrict__ h16,
                                                   __half* __restrict__ agg16, int n) {
    int node = (blockIdx.x * 256 + threadIdx.x) >> 6;
    if (node >= n) return;
    int lane = threadIdx.x & 63;
    int half = lane >> 5;
    int c4 = (lane & 31) * 4;
    int beg = rp[node], end = rp[node + 1];
    float4 A0 = make_float4(0.f, 0.f, 0.f, 0.f);
    float4 A1 = make_float4(0.f, 0.f, 0.f, 0.f);
    float4 A2 = make_float4(0.f, 0.f, 0.f, 0.f);
    float4 A3 = make_float4(0.f, 0.f, 0.f, 0.f);
    int j = beg + half;
    for (; j + 6 < end; j += 8) {
        int s0 = ci[j], s1 = ci[j + 2], s2 = ci[j + 4], s3 = ci[j + 6];
        float2 r0 = *(const float2*)(h16 + (size_t)s0 * HID + c4);
        float2 r1 = *(const float2*)(h16 + (size_t)s1 * HID + c4);
        float2 r2 = *(const float2*)(h16 + (size_t)s2 * HID + c4);
        float2 r3 = *(const float2*)(h16 + (size_t)s3 * HID + c4);
        const __half2* p0 = (const __half2*)&r0;
        const __half2* p1 = (const __half2*)&r1;
        const __half2* p2 = (const __half2*)&r2;
        const __half2* p3 = (const __half2*)&r3;
        float2 l0 = __half22float2(p0[0]), h0 = __half22float2(p0[1]);
        float2 l1 = __half22float2(p1[0]), h1 = __half22float2(p1[1]);
        float2 l2 = __half22float2(p2[0]), h2 = __half22float2(p2[1]);
        float2 l3 = __half22float2(p3[0]), h3 = __half22float2(p3[1]);
        A0.x += l0.x; A0.y += l0.y; A0.z += h0.x; A0.w += h0.y;
        A1.x += l1.x; A1.y += l1.y; A1.z += h1.x; A1.w += h1.y;
        A2.x += l2.x; A2.y += l2.y; A2.z += h2.x; A2.w += h2.y;
        A3.x += l3.x; A3.y += l3.y; A3.z += h3.x; A3.w += h3.y;
    }
    for (; j < end; j += 2) {
        int s0 = ci[j];
        float2 r0 = *(const float2*)(h16 + (size_t)s0 * HID + c4);
        const __half2* p0 = (const __half2*)&r0;
        float2 l0 = __half22float2(p0[0]), h0 = __half22float2(p0[1]);
        A0.x += l0.x; A0.y += l0.y; A0.z += h0.x; A0.w += h0.y;
    }
    float ax = A0.x + A1.x + A2.x + A3.x;
    float ay = A0.y + A1.y + A2.y + A3.y;
    float az = A0.z + A1.z + A2.z + A3.z;
    float aw = A0.w + A1.w + A2.w + A3.w;
    ax += __shfl_xor(ax, 32);
    ay += __shfl_xor(ay, 32);
    az += __shfl_xor(az, 32);
    aw += __shfl_xor(aw, 32);
    if (lane < 32) {
        float inv = 1.0f / fmaxf((float)(end - beg), 1.0f);
        __half2 o01 = __floats2half2_rn(ax * inv, ay * inv);
        __half2 o23 = __floats2half2_rn(az * inv, aw * inv);
        float2 pack;
        ((__half2*)&pack)[0] = o01;
        ((__half2*)&pack)[1] = o23;
        *(float2*)(agg16 + (size_t)node * HID + c4) = pack;
    }
}

// ---------------- layer 0 (R17 v1): fused 5-group 11-dim gather + dual matmul + LN + ReLU ----------------
__global__ __launch_bounds__(256) void layer0_kernel(
    const float* __restrict__ x, const int* __restrict__ rp, const int* __restrict__ ci,
    const float* __restrict__ w_l, const float* __restrict__ b_l, const float* __restrict__ w_r,
    const float* __restrict__ ln_w, const float* __restrict__ ln_b,
    __half* __restrict__ h16, int n)
{
    int node = (blockIdx.x * 256 + threadIdx.x) >> 6;
    int lane = threadIdx.x & 63;
    if (node >= n) return;
    int beg = rp[node], end = rp[node + 1];
    int g = lane / 11;
    int d = lane - g * 11;
    float acc0 = 0.f, acc1 = 0.f;
    int j = beg + g;
    if (g < 5) {
        for (; j + 5 < end; j += 10) {
            int s0 = ci[j], s1 = ci[j + 5];
            acc0 += x[(size_t)s0 * 11 + d];
            acc1 += x[(size_t)s1 * 11 + d];
        }
        for (; j < end; j += 5) {
            int s0 = ci[j];
            acc0 += x[(size_t)s0 * 11 + d];
        }
    }
    float acc = acc0 + acc1;
    float aggk = 0.f;
    #pragma unroll
    for (int gg = 0; gg < 5; ++gg) {
        aggk += __shfl(acc, (lane < 11) ? (lane + 11 * gg) : lane);
    }
    float inv = 1.0f / fmaxf((float)(end - beg), 1.0f);
    float v0 = b_l[lane], v1 = b_l[lane + 64];
    #pragma unroll
    for (int k = 0; k < 11; ++k) {
        float a  = __shfl(aggk, k) * inv;
        float xi = x[(size_t)node * 11 + k];
        v0 += a * w_l[k * HID + lane]      + xi * w_r[k * HID + lane];
        v1 += a * w_l[k * HID + lane + 64] + xi * w_r[k * HID + lane + 64];
    }
    float s = v0 + v1, s2 = v0 * v0 + v1 * v1;
    #pragma unroll
    for (int m = 1; m < 64; m <<= 1) { s += __shfl_xor(s, m); s2 += __shfl_xor(s2, m); }
    float mu  = s * (1.0f / HID);
    float var = s2 * (1.0f / HID) - mu * mu;
    float rstd = rsqrtf(var + 1e-5f);
    float o0 = fmaxf((v0 - mu) * rstd * ln_w[lane]      + ln_b[lane],      0.0f);
    float o1 = fmaxf((v1 - mu) * rstd * ln_w[lane + 64] + ln_b[lane + 64], 0.0f);
    h16[(size_t)node * HID + lane]      = __float2half_rn(o0);
    h16[(size_t)node * HID + lane + 64] = __float2half_rn(o1);
}

// ---------------- MFMA B-fragment weight pack ----------------
__global__ __launch_bounds__(256) void wfrag_kernel(const float* __restrict__ wl,
                                                    const float* __restrict__ wr,
                                                    __half* __restrict__ wf) {
    int idx = blockIdx.x * 256 + threadIdx.x;   // over 8*8*64 = 4096
    if (idx >= 4096) return;
    int kt = idx >> 9;
    int ct = (idx >> 6) & 7;
    int l  = idx & 63;
    int col = ct * 16 + (l & 15);
    int kbase = kt * 32 + (l >> 4) * 8;
    #pragma unroll
    for (int j = 0; j < 8; ++j) {
        int k = kbase + j;
        const float* W = (k < HID) ? wl : wr;
        int kk = k & (HID - 1);
        wf[(size_t)idx * 8 + j] = __float2half_rn(W[kk * HID + col]);
    }
}

// ---------------- cls weight pack ----------------
__global__ __launch_bounds__(256) void wpack_cls_kernel(const float* __restrict__ w0,
                                                        __half2* __restrict__ w0p) {
    int idx = blockIdx.x * 256 + threadIdx.x;   // over 64*64
    if (idx >= 64 * 64) return;
    int p = idx >> 6, c = idx & 63;
    w0p[idx] = __floats2half2_rn(w0[(2 * p) * 64 + c], w0[(2 * p + 1) * 64 + c]);
}

// ---------------- layers 1/2: MFMA GEMM (64 nodes/block, 4 waves x 16-row tiles) ----------------
__global__ __launch_bounds__(256) void layer_kernel(
    const __half* __restrict__ agg16, const __half* __restrict__ h16in,
    const __half* __restrict__ wf, const float* __restrict__ b_l,
    const float* __restrict__ ln_w, const float* __restrict__ ln_b,
    __half* __restrict__ h16out, int n)
{
    __shared__ __half lds[64][264];   // [node][agg(0..127) | h_in(128..255)]
    int base = blockIdx.x * 64;
    int tid = threadIdx.x;
    #pragma unroll
    for (int i = 0; i < 8; ++i) {
        int idx = tid + i * 256;
        int row = idx >> 5;
        int c4  = (idx & 31) * 4;
        int node = base + row;
        float2 a = make_float2(0.f, 0.f);
        float2 h = make_float2(0.f, 0.f);
        if (node < n) {
            a = *(const float2*)(agg16 + (size_t)node * HID + c4);
            h = *(const float2*)(h16in + (size_t)node * HID + c4);
        }
        *(float2*)&lds[row][c4]       = a;
        *(float2*)&lds[row][HID + c4] = h;
    }
    __syncthreads();

    int w = tid >> 6;
    int l = tid & 63;
    int g = l >> 4, cl = l & 15;

    f32x4 acc[8];
    #pragma unroll
    for (int ct = 0; ct < 8; ++ct) acc[ct] = (f32x4){0.f, 0.f, 0.f, 0.f};

    #pragma unroll
    for (int kt = 0; kt < 8; ++kt) {
        half8 a = *(const half8*)&lds[w * 16 + cl][kt * 32 + g * 8];
        #pragma unroll
        for (int ct = 0; ct < 8; ++ct) {
            half8 b = *(const half8*)(wf + ((size_t)(kt * 8 + ct) * 64 + l) * 8);
            acc[ct] = __builtin_amdgcn_mfma_f32_16x16x32_f16(a, b, acc[ct], 0, 0, 0);
        }
    }

    float bl8[8], gw8[8], gb8[8];
    #pragma unroll
    for (int ct = 0; ct < 8; ++ct) {
        bl8[ct] = b_l[ct * 16 + cl];
        gw8[ct] = ln_w[ct * 16 + cl];
        gb8[ct] = ln_b[ct * 16 + cl];
    }

    #pragma unroll
    for (int r = 0; r < 4; ++r) {
        int row = w * 16 + g * 4 + r;
        float v[8];
        float s = 0.f, s2 = 0.f;
        #pragma unroll
        for (int ct = 0; ct < 8; ++ct) {
            v[ct] = acc[ct][r] + bl8[ct];
            s += v[ct]; s2 += v[ct] * v[ct];
        }
        #pragma unroll
        for (int m = 1; m < 16; m <<= 1) { s += __shfl_xor(s, m); s2 += __shfl_xor(s2, m); }
        float mu  = s * (1.0f / HID);
        float var = s2 * (1.0f / HID) - mu * mu;
        float rstd = rsqrtf(var + 1e-5f);
        int node = base + row;
        if (node < n) {
            #pragma unroll
            for (int ct = 0; ct < 8; ++ct) {
                float o = fmaxf((v[ct] - mu) * rstd * gw8[ct] + gb8[ct], 0.f)
                          + __half2float(lds[row][HID + ct * 16 + cl]);
                h16out[(size_t)node * HID + ct * 16 + cl] = __float2half_rn(o);
            }
        }
    }
}

// ---------------- classifier: dot2, 32 nodes/block (8/wave), 2 accumulators ----------------
__global__ __launch_bounds__(256) void cls_kernel(
    const __half* __restrict__ h, const __half2* __restrict__ w0p, const float* __restrict__ b0,
    const float* __restrict__ w1, const float* __restrict__ b1, float* __restrict__ out, int n)
{
    __shared__ __half2 w0s[64 * 64];   // 16 KB, k-pair-packed
    int tid = threadIdx.x;
    #pragma unroll
    for (int i = 0; i < 16; ++i) w0s[tid + i * 256] = w0p[tid + i * 256];
    __syncthreads();
    int lane = tid & 63, wv = tid >> 6;
    float bb0 = b0[lane], ww1 = w1[lane], bb1 = b1[0];
    #pragma unroll 1
    for (int q = 0; q < 8; ++q) {
        int node = blockIdx.x * 32 + wv * 8 + q;
        if (node >= n) break;
        const __half2* hr = (const __half2*)(h + (size_t)node * HID);
        float s0 = 0.f, s1 = 0.f;
        #pragma unroll
        for (int p = 0; p < 64; p += 2) {
            s0 = fdot2(hr[p],     w0s[(p + 0) * 64 + lane], s0);
            s1 = fdot2(hr[p + 1], w0s[(p + 1) * 64 + lane], s1);
        }
        float s = fmaxf(s0 + s1 + bb0, 0.f);
        float t = s * ww1;
        #pragma unroll
        for (int m = 1; m < 64; m <<= 1) t += __shfl_xor(t, m);
        if (lane == 0) out[node] = t + bb1;
    }
}

extern "C" void kernel_launch(void* const* d_in, const int* in_sizes, int n_in,
                              void* d_out, int out_size, void* d_ws, size_t ws_size,
                              hipStream_t stream) {
    const float* x  = (const float*)d_in[0];
    const int*   ei = (const int*)d_in[1];     // integer inputs arrive as int32
    const float* w_l0 = (const float*)d_in[2];
    const float* b_l0 = (const float*)d_in[3];
    const float* w_r0 = (const float*)d_in[4];
    const float* lnw0 = (const float*)d_in[5];
    const float* lnb0 = (const float*)d_in[6];
    const float* w_l1 = (const float*)d_in[7];
    const float* b_l1 = (const float*)d_in[8];
    const float* w_r1 = (const float*)d_in[9];
    const float* lnw1 = (const float*)d_in[10];
    const float* lnb1 = (const float*)d_in[11];
    const float* w_l2 = (const float*)d_in[12];
    const float* b_l2 = (const float*)d_in[13];
    const float* w_r2 = (const float*)d_in[14];
    const float* lnw2 = (const float*)d_in[15];
    const float* lnb2 = (const float*)d_in[16];
    const float* c_w0 = (const float*)d_in[17];
    const float* c_b0 = (const float*)d_in[18];
    const float* c_w1 = (const float*)d_in[19];
    const float* c_b1 = (const float*)d_in[20];
    float* out = (float*)d_out;

    int N = in_sizes[0] / 11;
    int E = in_sizes[1] / 2;
    int nb = (N + 255) / 256;

    // workspace: [deg: N][rp: N+1][cursor: N][csr: E][part: nb]
    //            [h16][agg16][wf1][wf2][w0p]
    int*     deg    = (int*)d_ws;
    int*     rp     = deg + N;
    int*     cursor = rp + (N + 1);
    int*     csr    = cursor + N;
    int*     part   = csr + E;
    __half*  h16    = (__half*)(part + ((nb + 63) & ~63));
    __half*  agg16  = h16 + (size_t)N * HID;
    __half*  wf1    = agg16 + (size_t)N * HID;
    __half*  wf2    = wf1 + 4096 * 8;
    __half2* w0p    = (__half2*)(wf2 + 4096 * 8);

    // ---- CSR build (dst-range partitioned across XCDs) + weight packs ----
    int n4 = (N + 3) / 4;   // over-zeroing <=3 ints into rp is harmless (rp rewritten)
    zero_kernel<<<(n4 + 255) / 256, 256, 0, stream>>>((int4*)deg, n4);
    deg_kernel<<<8 * 512, 256, 0, stream>>>(ei, deg, E, N);
    part_kernel<<<nb, 256, 0, stream>>>(deg, part, N);
    scanpart_kernel<<<1, 1024, 0, stream>>>(part, nb);
    rp_kernel<<<nb, 256, 0, stream>>>(deg, part, rp, cursor, N);
    fill_kernel<<<8 * 512, 256, 0, stream>>>(ei, cursor, csr, E, N);
    wfrag_kernel<<<16, 256, 0, stream>>>(w_l1, w_r1, wf1);
    wfrag_kernel<<<16, 256, 0, stream>>>(w_l2, w_r2, wf2);
    wpack_cls_kernel<<<16, 256, 0, stream>>>(c_w0, w0p);

    int nodeBlocks = (N + 3) / 4;

    // ---- layer 0 ----  fused gather+mm -> h16
    layer0_kernel<<<nodeBlocks, 256, 0, stream>>>(x, rp, csr, w_l0, b_l0, w_r0, lnw0, lnb0, h16, N);

    // ---- layer 1 ----  gather(h16)->agg16 ; layer(agg16, h16) -> h16
    aggp_kernel<<<nodeBlocks, 256, 0, stream>>>(rp, csr, h16, agg16, N);
    layer_kernel<<<(N + 63) / 64, 256, 0, stream>>>(agg16, h16, wf1, b_l1, lnw1, lnb1, h16, N);

    // ---- layer 2 ----
    aggp_kernel<<<nodeBlocks, 256, 0, stream>>>(rp, csr, h16, agg16, N);
    layer_kernel<<<(N + 63) / 64, 256, 0, stream>>>(agg16, h16, wf2, b_l2, lnw2, lnb2, h16, N);

    // ---- classifier ----
    cls_kernel<<<(N + 31) / 32, 256, 0, stream>>>(h16, w0p, c_b0, c_w1, c_b1, out, N);
}

// Round 21
// 269.525 us; speedup vs baseline: 1.0409x; 1.0157x over previous
//
#include <hip/hip_runtime.h>
#include <hip/hip_fp16.h>

#define HID 128

typedef _Float16 h2_t __attribute__((ext_vector_type(2)));
typedef _Float16 half8 __attribute__((ext_vector_type(8)));
typedef float f32x4 __attribute__((ext_vector_type(4)));

static __device__ __forceinline__ float fdot2(__half2 a, __half2 b, float c) {
    return __builtin_amdgcn_fdot2(__builtin_bit_cast(h2_t, a), __builtin_bit_cast(h2_t, b), c, false);
}

// ---------------- fast zero ----------------
__global__ __launch_bounds__(256) void zero_kernel(int4* __restrict__ p, int n4) {
    int i = blockIdx.x * 256 + threadIdx.x;
    if (i < n4) p[i] = make_int4(0, 0, 0, 0);
}

// ---------------- degree histogram, XCD/dst-range partitioned ----------------
__global__ __launch_bounds__(256) void deg_kernel(const int* __restrict__ ei,
                                                  int* __restrict__ deg, int E, int n) {
    int grp  = blockIdx.x & 7;
    int blk  = blockIdx.x >> 3;
    int nblk = gridDim.x >> 3;
    int lo = (int)(((long long)n * grp) >> 3);
    int hi = (int)(((long long)n * (grp + 1)) >> 3);
    for (int e = blk * 256 + threadIdx.x; e < E; e += nblk * 256) {
        int dst = ei[E + e];
        if (dst >= lo && dst < hi) atomicAdd(&deg[dst], 1);
    }
}

// ---------------- scan stage 1 ----------------
__global__ __launch_bounds__(256) void part_kernel(const int* __restrict__ deg,
                                                   int* __restrict__ part, int n) {
    int i = blockIdx.x * 256 + threadIdx.x;
    int v = (i < n) ? deg[i] : 0;
    #pragma unroll
    for (int m = 1; m < 64; m <<= 1) v += __shfl_xor(v, m);
    __shared__ int w[4];
    int lane = threadIdx.x & 63, wv = threadIdx.x >> 6;
    if (lane == 0) w[wv] = v;
    __syncthreads();
    if (threadIdx.x == 0) part[blockIdx.x] = w[0] + w[1] + w[2] + w[3];
}

// ---------------- scan stage 2 ----------------
__global__ __launch_bounds__(1024) void scanpart_kernel(int* __restrict__ part, int nb) {
    __shared__ int s[1024];
    int t = threadIdx.x;
    int v = (t < nb) ? part[t] : 0;
    int orig = v;
    s[t] = v;
    __syncthreads();
    for (int off = 1; off < 1024; off <<= 1) {
        int u = (t >= off) ? s[t - off] : 0;
        __syncthreads();
        s[t] += u;
        __syncthreads();
    }
    if (t < nb) part[t] = s[t] - orig;   // exclusive
}

// ---------------- scan stage 3 ----------------
__global__ __launch_bounds__(256) void rp_kernel(const int* __restrict__ deg,
                                                 const int* __restrict__ part,
                                                 int* __restrict__ rp,
                                                 int* __restrict__ cursor, int n) {
    int tid = threadIdx.x, lane = tid & 63, wv = tid >> 6;
    int i = blockIdx.x * 256 + tid;
    int v = (i < n) ? deg[i] : 0;
    int orig = v;
    #pragma unroll
    for (int off = 1; off < 64; off <<= 1) {
        int t = __shfl_up(v, off);
        if (lane >= off) v += t;
    }
    __shared__ int wsum[4];
    if (lane == 63) wsum[wv] = v;
    __syncthreads();
    int wbase = 0;
    #pragma unroll
    for (int w = 0; w < 4; ++w) if (w < wv) wbase += wsum[w];
    int excl = part[blockIdx.x] + wbase + v - orig;
    if (i < n) { rp[i] = excl; cursor[i] = excl; }
    if (i == n - 1) rp[n] = excl + orig;
}

// ---------------- CSR fill, XCD/dst-range partitioned ----------------
__global__ __launch_bounds__(256) void fill_kernel(const int* __restrict__ ei,
                                                   int* __restrict__ cursor,
                                                   int* __restrict__ csr_src, int E, int n) {
    int grp  = blockIdx.x & 7;
    int blk  = blockIdx.x >> 3;
    int nblk = gridDim.x >> 3;
    int lo = (int)(((long long)n * grp) >> 3);
    int hi = (int)(((long long)n * (grp + 1)) >> 3);
    for (int e = blk * 256 + threadIdx.x; e < E; e += nblk * 256) {
        int dst = ei[E + e];
        if (dst >= lo && dst < hi) {
            int pos = atomicAdd(&cursor[dst], 1);
            csr_src[pos] = ei[e];
        }
    }
}

// ---------------- 128-dim pull aggregation v1 (R17): float2/lane, 8 accumulators ----------------
__global__ __launch_bounds__(256) void aggp_kernel(const int* __restrict__ rp,
                                                   const int* __restrict__ ci,
                                                   const __half* __restrict__ h16,
                                                   __half* __restrict__ agg16, int n) {
    int node = (blockIdx.x * 256 + threadIdx.x) >> 6;
    if (node >= n) return;
    int lane = threadIdx.x & 63;
    float2 a0 = make_float2(0.f, 0.f), a1 = make_float2(0.f, 0.f);
    float2 a2 = make_float2(0.f, 0.f), a3 = make_float2(0.f, 0.f);
    float2 a4 = make_float2(0.f, 0.f), a5 = make_float2(0.f, 0.f);
    float2 a6 = make_float2(0.f, 0.f), a7 = make_float2(0.f, 0.f);
    int beg = rp[node], end = rp[node + 1];
    int j = beg;
    for (; j + 7 < end; j += 8) {
        int s0 = ci[j],     s1 = ci[j + 1], s2 = ci[j + 2], s3 = ci[j + 3];
        int s4 = ci[j + 4], s5 = ci[j + 5], s6 = ci[j + 6], s7 = ci[j + 7];
        float2 f0 = __half22float2(*(const __half2*)(h16 + (size_t)s0 * HID + lane * 2));
        float2 f1 = __half22float2(*(const __half2*)(h16 + (size_t)s1 * HID + lane * 2));
        float2 f2 = __half22float2(*(const __half2*)(h16 + (size_t)s2 * HID + lane * 2));
        float2 f3 = __half22float2(*(const __half2*)(h16 + (size_t)s3 * HID + lane * 2));
        float2 f4 = __half22float2(*(const __half2*)(h16 + (size_t)s4 * HID + lane * 2));
        float2 f5 = __half22float2(*(const __half2*)(h16 + (size_t)s5 * HID + lane * 2));
        float2 f6 = __half22float2(*(const __half2*)(h16 + (size_t)s6 * HID + lane * 2));
        float2 f7 = __half22float2(*(const __half2*)(h16 + (size_t)s7 * HID + lane * 2));
        a0.x += f0.x; a0.y += f0.y;  a1.x += f1.x; a1.y += f1.y;
        a2.x += f2.x; a2.y += f2.y;  a3.x += f3.x; a3.y += f3.y;
        a4.x += f4.x; a4.y += f4.y;  a5.x += f5.x; a5.y += f5.y;
        a6.x += f6.x; a6.y += f6.y;  a7.x += f7.x; a7.y += f7.y;
    }
    for (; j + 3 < end; j += 4) {
        int s0 = ci[j], s1 = ci[j + 1], s2 = ci[j + 2], s3 = ci[j + 3];
        float2 f0 = __half22float2(*(const __half2*)(h16 + (size_t)s0 * HID + lane * 2));
        float2 f1 = __half22float2(*(const __half2*)(h16 + (size_t)s1 * HID + lane * 2));
        float2 f2 = __half22float2(*(const __half2*)(h16 + (size_t)s2 * HID + lane * 2));
        float2 f3 = __half22float2(*(const __half2*)(h16 + (size_t)s3 * HID + lane * 2));
        a0.x += f0.x; a0.y += f0.y;  a1.x += f1.x; a1.y += f1.y;
        a2.x += f2.x; a2.y += f2.y;  a3.x += f3.x; a3.y += f3.y;
    }
    for (; j < end; ++j) {
        int s0 = ci[j];
        float2 f0 = __half22float2(*(const __half2*)(h16 + (size_t)s0 * HID + lane * 2));
        a0.x += f0.x; a0.y += f0.y;
    }
    float inv = 1.0f / fmaxf((float)(end - beg), 1.0f);
    float ox = (a0.x + a1.x + a2.x + a3.x + a4.x + a5.x + a6.x + a7.x) * inv;
    float oy = (a0.y + a1.y + a2.y + a3.y + a4.y + a5.y + a6.y + a7.y) * inv;
    *(__half2*)(agg16 + (size_t)node * HID + lane * 2) = __floats2half2_rn(ox, oy);
}

// ---------------- layer 0 (R17 v1): fused 5-group 11-dim gather + dual matmul + LN + ReLU ----------------
__global__ __launch_bounds__(256) void layer0_kernel(
    const float* __restrict__ x, const int* __restrict__ rp, const int* __restrict__ ci,
    const float* __restrict__ w_l, const float* __restrict__ b_l, const float* __restrict__ w_r,
    const float* __restrict__ ln_w, const float* __restrict__ ln_b,
    __half* __restrict__ h16, int n)
{
    int node = (blockIdx.x * 256 + threadIdx.x) >> 6;
    int lane = threadIdx.x & 63;
    if (node >= n) return;
    int beg = rp[node], end = rp[node + 1];
    int g = lane / 11;
    int d = lane - g * 11;
    float acc0 = 0.f, acc1 = 0.f;
    int j = beg + g;
    if (g < 5) {
        for (; j + 5 < end; j += 10) {
            int s0 = ci[j], s1 = ci[j + 5];
            acc0 += x[(size_t)s0 * 11 + d];
            acc1 += x[(size_t)s1 * 11 + d];
        }
        for (; j < end; j += 5) {
            int s0 = ci[j];
            acc0 += x[(size_t)s0 * 11 + d];
        }
    }
    float acc = acc0 + acc1;
    float aggk = 0.f;
    #pragma unroll
    for (int gg = 0; gg < 5; ++gg) {
        aggk += __shfl(acc, (lane < 11) ? (lane + 11 * gg) : lane);
    }
    float inv = 1.0f / fmaxf((float)(end - beg), 1.0f);
    float v0 = b_l[lane], v1 = b_l[lane + 64];
    #pragma unroll
    for (int k = 0; k < 11; ++k) {
        float a  = __shfl(aggk, k) * inv;
        float xi = x[(size_t)node * 11 + k];
        v0 += a * w_l[k * HID + lane]      + xi * w_r[k * HID + lane];
        v1 += a * w_l[k * HID + lane + 64] + xi * w_r[k * HID + lane + 64];
    }
    float s = v0 + v1, s2 = v0 * v0 + v1 * v1;
    #pragma unroll
    for (int m = 1; m < 64; m <<= 1) { s += __shfl_xor(s, m); s2 += __shfl_xor(s2, m); }
    float mu  = s * (1.0f / HID);
    float var = s2 * (1.0f / HID) - mu * mu;
    float rstd = rsqrtf(var + 1e-5f);
    float o0 = fmaxf((v0 - mu) * rstd * ln_w[lane]      + ln_b[lane],      0.0f);
    float o1 = fmaxf((v1 - mu) * rstd * ln_w[lane + 64] + ln_b[lane + 64], 0.0f);
    h16[(size_t)node * HID + lane]      = __float2half_rn(o0);
    h16[(size_t)node * HID + lane + 64] = __float2half_rn(o1);
}

// ---------------- MFMA B-fragment weight pack ----------------
__global__ __launch_bounds__(256) void wfrag_kernel(const float* __restrict__ wl,
                                                    const float* __restrict__ wr,
                                                    __half* __restrict__ wf) {
    int idx = blockIdx.x * 256 + threadIdx.x;   // over 8*8*64 = 4096
    if (idx >= 4096) return;
    int kt = idx >> 9;
    int ct = (idx >> 6) & 7;
    int l  = idx & 63;
    int col = ct * 16 + (l & 15);
    int kbase = kt * 32 + (l >> 4) * 8;
    #pragma unroll
    for (int j = 0; j < 8; ++j) {
        int k = kbase + j;
        const float* W = (k < HID) ? wl : wr;
        int kk = k & (HID - 1);
        wf[(size_t)idx * 8 + j] = __float2half_rn(W[kk * HID + col]);
    }
}

// ---------------- cls weight pack ----------------
__global__ __launch_bounds__(256) void wpack_cls_kernel(const float* __restrict__ w0,
                                                        __half2* __restrict__ w0p) {
    int idx = blockIdx.x * 256 + threadIdx.x;   // over 64*64
    if (idx >= 64 * 64) return;
    int p = idx >> 6, c = idx & 63;
    w0p[idx] = __floats2half2_rn(w0[(2 * p) * 64 + c], w0[(2 * p + 1) * 64 + c]);
}

// ---------------- layers 1/2: MFMA GEMM (64 nodes/block, 4 waves x 16-row tiles) ----------------
__global__ __launch_bounds__(256) void layer_kernel(
    const __half* __restrict__ agg16, const __half* __restrict__ h16in,
    const __half* __restrict__ wf, const float* __restrict__ b_l,
    const float* __restrict__ ln_w, const float* __restrict__ ln_b,
    __half* __restrict__ h16out, int n)
{
    __shared__ __half lds[64][264];   // [node][agg(0..127) | h_in(128..255)]
    int base = blockIdx.x * 64;
    int tid = threadIdx.x;
    #pragma unroll
    for (int i = 0; i < 8; ++i) {
        int idx = tid + i * 256;
        int row = idx >> 5;
        int c4  = (idx & 31) * 4;
        int node = base + row;
        float2 a = make_float2(0.f, 0.f);
        float2 h = make_float2(0.f, 0.f);
        if (node < n) {
            a = *(const float2*)(agg16 + (size_t)node * HID + c4);
            h = *(const float2*)(h16in + (size_t)node * HID + c4);
        }
        *(float2*)&lds[row][c4]       = a;
        *(float2*)&lds[row][HID + c4] = h;
    }
    __syncthreads();

    int w = tid >> 6;
    int l = tid & 63;
    int g = l >> 4, cl = l & 15;

    f32x4 acc[8];
    #pragma unroll
    for (int ct = 0; ct < 8; ++ct) acc[ct] = (f32x4){0.f, 0.f, 0.f, 0.f};

    #pragma unroll
    for (int kt = 0; kt < 8; ++kt) {
        half8 a = *(const half8*)&lds[w * 16 + cl][kt * 32 + g * 8];
        #pragma unroll
        for (int ct = 0; ct < 8; ++ct) {
            half8 b = *(const half8*)(wf + ((size_t)(kt * 8 + ct) * 64 + l) * 8);
            acc[ct] = __builtin_amdgcn_mfma_f32_16x16x32_f16(a, b, acc[ct], 0, 0, 0);
        }
    }

    float bl8[8], gw8[8], gb8[8];
    #pragma unroll
    for (int ct = 0; ct < 8; ++ct) {
        bl8[ct] = b_l[ct * 16 + cl];
        gw8[ct] = ln_w[ct * 16 + cl];
        gb8[ct] = ln_b[ct * 16 + cl];
    }

    #pragma unroll
    for (int r = 0; r < 4; ++r) {
        int row = w * 16 + g * 4 + r;
        float v[8];
        float s = 0.f, s2 = 0.f;
        #pragma unroll
        for (int ct = 0; ct < 8; ++ct) {
            v[ct] = acc[ct][r] + bl8[ct];
            s += v[ct]; s2 += v[ct] * v[ct];
        }
        #pragma unroll
        for (int m = 1; m < 16; m <<= 1) { s += __shfl_xor(s, m); s2 += __shfl_xor(s2, m); }
        float mu  = s * (1.0f / HID);
        float var = s2 * (1.0f / HID) - mu * mu;
        float rstd = rsqrtf(var + 1e-5f);
        int node = base + row;
        if (node < n) {
            #pragma unroll
            for (int ct = 0; ct < 8; ++ct) {
                float o = fmaxf((v[ct] - mu) * rstd * gw8[ct] + gb8[ct], 0.f)
                          + __half2float(lds[row][HID + ct * 16 + cl]);
                h16out[(size_t)node * HID + ct * 16 + cl] = __float2half_rn(o);
            }
        }
    }
}

// ---------------- classifier (R17): dot2, 16 nodes/block (4/wave), 2 accumulators ----------------
__global__ __launch_bounds__(256) void cls_kernel(
    const __half* __restrict__ h, const __half2* __restrict__ w0p, const float* __restrict__ b0,
    const float* __restrict__ w1, const float* __restrict__ b1, float* __restrict__ out, int n)
{
    __shared__ __half2 w0s[64 * 64];   // 16 KB, k-pair-packed
    int tid = threadIdx.x;
    #pragma unroll
    for (int i = 0; i < 16; ++i) w0s[tid + i * 256] = w0p[tid + i * 256];
    __syncthreads();
    int lane = tid & 63, wv = tid >> 6;
    float bb0 = b0[lane], ww1 = w1[lane], bb1 = b1[0];
    #pragma unroll 1
    for (int q = 0; q < 4; ++q) {
        int node = blockIdx.x * 16 + wv * 4 + q;
        if (node >= n) break;
        const __half2* hr = (const __half2*)(h + (size_t)node * HID);
        float s0 = 0.f, s1 = 0.f;
        #pragma unroll
        for (int p = 0; p < 64; p += 2) {
            s0 = fdot2(hr[p],     w0s[(p + 0) * 64 + lane], s0);
            s1 = fdot2(hr[p + 1], w0s[(p + 1) * 64 + lane], s1);
        }
        float s = fmaxf(s0 + s1 + bb0, 0.f);
        float t = s * ww1;
        #pragma unroll
        for (int m = 1; m < 64; m <<= 1) t += __shfl_xor(t, m);
        if (lane == 0) out[node] = t + bb1;
    }
}

extern "C" void kernel_launch(void* const* d_in, const int* in_sizes, int n_in,
                              void* d_out, int out_size, void* d_ws, size_t ws_size,
                              hipStream_t stream) {
    const float* x  = (const float*)d_in[0];
    const int*   ei = (const int*)d_in[1];     // integer inputs arrive as int32
    const float* w_l0 = (const float*)d_in[2];
    const float* b_l0 = (const float*)d_in[3];
    const float* w_r0 = (const float*)d_in[4];
    const float* lnw0 = (const float*)d_in[5];
    const float* lnb0 = (const float*)d_in[6];
    const float* w_l1 = (const float*)d_in[7];
    const float* b_l1 = (const float*)d_in[8];
    const float* w_r1 = (const float*)d_in[9];
    const float* lnw1 = (const float*)d_in[10];
    const float* lnb1 = (const float*)d_in[11];
    const float* w_l2 = (const float*)d_in[12];
    const float* b_l2 = (const float*)d_in[13];
    const float* w_r2 = (const float*)d_in[14];
    const float* lnw2 = (const float*)d_in[15];
    const float* lnb2 = (const float*)d_in[16];
    const float* c_w0 = (const float*)d_in[17];
    const float* c_b0 = (const float*)d_in[18];
    const float* c_w1 = (const float*)d_in[19];
    const float* c_b1 = (const float*)d_in[20];
    float* out = (float*)d_out;

    int N = in_sizes[0] / 11;
    int E = in_sizes[1] / 2;
    int nb = (N + 255) / 256;

    // workspace: [deg: N][rp: N+1][cursor: N][csr: E][part: nb]
    //            [h16][agg16][wf1][wf2][w0p]
    int*     deg    = (int*)d_ws;
    int*     rp     = deg + N;
    int*     cursor = rp + (N + 1);
    int*     csr    = cursor + N;
    int*     part   = csr + E;
    __half*  h16    = (__half*)(part + ((nb + 63) & ~63));
    __half*  agg16  = h16 + (size_t)N * HID;
    __half*  wf1    = agg16 + (size_t)N * HID;
    __half*  wf2    = wf1 + 4096 * 8;
    __half2* w0p    = (__half2*)(wf2 + 4096 * 8);

    // ---- CSR build (dst-range partitioned across XCDs) + weight packs ----
    int n4 = (N + 3) / 4;   // over-zeroing <=3 ints into rp is harmless (rp rewritten)
    zero_kernel<<<(n4 + 255) / 256, 256, 0, stream>>>((int4*)deg, n4);
    deg_kernel<<<8 * 512, 256, 0, stream>>>(ei, deg, E, N);
    part_kernel<<<nb, 256, 0, stream>>>(deg, part, N);
    scanpart_kernel<<<1, 1024, 0, stream>>>(part, nb);
    rp_kernel<<<nb, 256, 0, stream>>>(deg, part, rp, cursor, N);
    fill_kernel<<<8 * 512, 256, 0, stream>>>(ei, cursor, csr, E, N);
    wfrag_kernel<<<16, 256, 0, stream>>>(w_l1, w_r1, wf1);
    wfrag_kernel<<<16, 256, 0, stream>>>(w_l2, w_r2, wf2);
    wpack_cls_kernel<<<16, 256, 0, stream>>>(c_w0, w0p);

    int nodeBlocks = (N + 3) / 4;

    // ---- layer 0 ----  fused gather+mm -> h16
    layer0_kernel<<<nodeBlocks, 256, 0, stream>>>(x, rp, csr, w_l0, b_l0, w_r0, lnw0, lnb0, h16, N);

    // ---- layer 1 ----  gather(h16)->agg16 ; layer(agg16, h16) -> h16
    aggp_kernel<<<nodeBlocks, 256, 0, stream>>>(rp, csr, h16, agg16, N);
    layer_kernel<<<(N + 63) / 64, 256, 0, stream>>>(agg16, h16, wf1, b_l1, lnw1, lnb1, h16, N);

    // ---- layer 2 ----
    aggp_kernel<<<nodeBlocks, 256, 0, stream>>>(rp, csr, h16, agg16, N);
    layer_kernel<<<(N + 63) / 64, 256, 0, stream>>>(agg16, h16, wf2, b_l2, lnw2, lnb2, h16, N);

    // ---- classifier ----
    cls_kernel<<<(N + 15) / 16, 256, 0, stream>>>(h16, w0p, c_b0, c_w1, c_b1, out, N);
}